// Round 1
// baseline (178.080 us; speedup 1.0000x reference)
//
#include <hip/hip_runtime.h>
#include <math.h>

// TDVP_V2: BATCH=16384 independent chains, N=64 sites, D=4, DIN=DOUT=2.
// Per batch b:
//   xn[n]    = x[b,n,:]/||x[b,n,:]||
//   M[n]     = xn0*A[n,:,:,0] + xn1*A[n,:,:,1]            (4x4)
//   vL[n]    = e0^T M[0]...M[n-1]        (normalized, +eps)
//   Ar[n]    = M[n+1]...M[63] e0         (normalized, +eps)
//   H[n,j,k] = sum_{i,l} vl_i B[n,i,l,j,k] ar_l   (vl->e0 at n=0, ar->e0 at n=63)
//   H        = relu(nan_to_0(s*H/(||H||_F+eps)))
//   y[b,n,j] = sum_k H[j,k] xn[k]
//
// One thread per batch element. block=64, grid=256 -> 1 wave per CU.
// Right scan stores normalized Ar in LDS (63*64 float4 = 63KB, lane-private
// slots, contiguous b128 access -> conflict-free, no barriers needed).

#define NSITES 64
#define EPS 1e-6f

__global__ __launch_bounds__(64, 1)
void tdvp_kernel(const float* __restrict__ x,
                 const float* __restrict__ A,
                 const float* __restrict__ Bw,
                 const float* __restrict__ scale,
                 float* __restrict__ y,
                 int batch)
{
    __shared__ float4 arbuf[63 * 64];   // [site 0..62][lane]
    const int lane = threadIdx.x;
    const int b = blockIdx.x * 64 + lane;
    if (b >= batch) return;

    const float s = scale[0];
    const float* xb = x + (size_t)b * (NSITES * 2);
    float*       yb = y + (size_t)b * (NSITES * 2);

    // ---------------- right-to-left scan: Ar[n] = norm(M[n+1..63] e0) -------
    float u0 = 1.f, u1 = 0.f, u2 = 0.f, u3 = 0.f;
    float2 xc = *(const float2*)(xb + 63 * 2);          // x at site 63
    #pragma unroll 1
    for (int n = 62; n >= 0; --n) {
        float2 xnx = *(const float2*)(xb + n * 2);      // prefetch next site
        const float inr = 1.f / sqrtf(xc.x * xc.x + xc.y * xc.y);
        const float xn0 = xc.x * inr, xn1 = xc.y * inr;
        const float* Ap = A + (n + 1) * 32;             // A[site], uniform addr
        float uu[4] = {u0, u1, u2, u3};
        float vv[4];
        #pragma unroll
        for (int i = 0; i < 4; ++i) {                   // u' = M u
            float acc = 0.f;
            #pragma unroll
            for (int j = 0; j < 4; ++j) {
                float m = fmaf(xn1, Ap[(i * 4 + j) * 2 + 1], xn0 * Ap[(i * 4 + j) * 2]);
                acc = fmaf(m, uu[j], acc);
            }
            vv[i] = acc;
        }
        u0 = vv[0]; u1 = vv[1]; u2 = vv[2]; u3 = vv[3];
        const float rn = 1.f / (sqrtf(u0*u0 + u1*u1 + u2*u2 + u3*u3) + EPS);
        arbuf[n * 64 + lane] = make_float4(u0 * rn, u1 * rn, u2 * rn, u3 * rn);
        xc = xnx;
    }

    // ---------------- left-to-right scan + H + y ----------------------------
    float w0 = 0.f, w1 = 0.f, w2 = 0.f, w3 = 0.f;       // raw e0^T M[0..n-1]
    xc = *(const float2*)(xb);                          // x at site 0
    float4 arc = arbuf[lane];                           // Ar[0]
    #pragma unroll 1
    for (int n = 0; n < NSITES; ++n) {
        float2 xnx = xc;
        float4 arn = make_float4(1.f, 0.f, 0.f, 0.f);
        if (n < 63) xnx = *(const float2*)(xb + (n + 1) * 2);   // prefetch
        if (n < 62) arn = arbuf[(n + 1) * 64 + lane];           // prefetch

        const float inr = 1.f / sqrtf(xc.x * xc.x + xc.y * xc.y);
        const float xn0 = xc.x * inr, xn1 = xc.y * inr;

        float vls[4];
        if (n == 0) { vls[0] = 1.f; vls[1] = vls[2] = vls[3] = 0.f; }
        else {
            const float rw = 1.f / (sqrtf(w0*w0 + w1*w1 + w2*w2 + w3*w3) + EPS);
            vls[0] = w0 * rw; vls[1] = w1 * rw; vls[2] = w2 * rw; vls[3] = w3 * rw;
        }
        float ars[4] = {arc.x, arc.y, arc.z, arc.w};
        if (n == 63) { ars[0] = 1.f; ars[1] = ars[2] = ars[3] = 0.f; }

        // H[j][k] = sum_{i,l} vl_i * ar_l * B[n,i,l,j,k]
        const float* Bp = Bw + n * 64;                  // uniform addr
        float H00 = 0.f, H01 = 0.f, H10 = 0.f, H11 = 0.f;
        #pragma unroll
        for (int i = 0; i < 4; ++i) {
            #pragma unroll
            for (int l = 0; l < 4; ++l) {
                const float c = vls[i] * ars[l];
                const float* bb = Bp + (i * 4 + l) * 4;
                H00 = fmaf(c, bb[0], H00);
                H01 = fmaf(c, bb[1], H01);
                H10 = fmaf(c, bb[2], H10);
                H11 = fmaf(c, bb[3], H11);
            }
        }
        const float rh = s / (sqrtf(H00*H00 + H01*H01 + H10*H10 + H11*H11) + EPS);
        H00 *= rh; H01 *= rh; H10 *= rh; H11 *= rh;
        if (__builtin_isnan(H00)) H00 = 0.f;
        if (__builtin_isnan(H01)) H01 = 0.f;
        if (__builtin_isnan(H10)) H10 = 0.f;
        if (__builtin_isnan(H11)) H11 = 0.f;
        H00 = fmaxf(H00, 0.f); H01 = fmaxf(H01, 0.f);
        H10 = fmaxf(H10, 0.f); H11 = fmaxf(H11, 0.f);

        float2 yo;
        yo.x = fmaf(H01, xn1, H00 * xn0);
        yo.y = fmaf(H11, xn1, H10 * xn0);
        *(float2*)(yb + n * 2) = yo;

        // advance w across site n: w' = w^T M[n]  (row-vector times matrix)
        const float* Ap = A + n * 32;                   // uniform addr
        if (n == 0) {
            w0 = fmaf(xn1, Ap[1], xn0 * Ap[0]);
            w1 = fmaf(xn1, Ap[3], xn0 * Ap[2]);
            w2 = fmaf(xn1, Ap[5], xn0 * Ap[4]);
            w3 = fmaf(xn1, Ap[7], xn0 * Ap[6]);
        } else {
            float ww[4] = {w0, w1, w2, w3};
            float tt[4] = {0.f, 0.f, 0.f, 0.f};
            #pragma unroll
            for (int i = 0; i < 4; ++i) {
                #pragma unroll
                for (int j = 0; j < 4; ++j) {
                    float m = fmaf(xn1, Ap[(i * 4 + j) * 2 + 1], xn0 * Ap[(i * 4 + j) * 2]);
                    tt[j] = fmaf(ww[i], m, tt[j]);
                }
            }
            w0 = tt[0]; w1 = tt[1]; w2 = tt[2]; w3 = tt[3];
        }
        xc = xnx;
        arc = arn;
    }
}

extern "C" void kernel_launch(void* const* d_in, const int* in_sizes, int n_in,
                              void* d_out, int out_size, void* d_ws, size_t ws_size,
                              hipStream_t stream) {
    const float* x     = (const float*)d_in[0];
    const float* A     = (const float*)d_in[1];
    const float* B     = (const float*)d_in[2];
    const float* scale = (const float*)d_in[3];
    float* y = (float*)d_out;
    const int batch  = in_sizes[0] / (NSITES * 2);   // 16384
    const int blocks = (batch + 63) / 64;            // 256 -> 1 wave per CU
    tdvp_kernel<<<blocks, 64, 0, stream>>>(x, A, B, scale, y, batch);
}

// Round 2
// 103.357 us; speedup vs baseline: 1.7230x; 1.7230x over previous
//
#include <hip/hip_runtime.h>
#include <hip/hip_fp16.h>
#include <math.h>

// TDVP_V2: BATCH=16384 chains, N=64 sites, D=4, DIN=DOUT=2.
// v2 structure: block = 256 threads handles 64 batches.
//   wave 0: right scan  Ar[n] = norm(M[n+1..63] e0)      -> sAr (half4)
//   wave 1: left  scan  vL[n] = norm(e0^T M[0..n-1])     -> sVl (half4)
//   (waves 2,3 park at the barrier)
//   then all 4 waves: per-site epilogue H = vl.B.ar, norm/nan/relu, y = H.xn
// Scans double-buffer x in 8-site float4 chunks and batch A loads 8 sites
// at a time so global latency is paid once per chunk, not per load.
// LDS: 2 * 63*64*8 B = 64512 B (half4), within the 64 KiB static line.

#define NSITES 64
#define EPS 1e-6f

__global__ __launch_bounds__(256)
void tdvp_kernel(const float* __restrict__ x,
                 const float* __restrict__ A,
                 const float* __restrict__ Bw,
                 const float* __restrict__ scale,
                 float* __restrict__ y)
{
    __shared__ __half2 sAr[63 * 64 * 2];   // Ar[site 0..62][lane] as 2x half2
    __shared__ __half2 sVl[63 * 64 * 2];   // vL[site 1..63][lane] (index n-1)

    const int tid  = threadIdx.x;
    const int lane = tid & 63;
    const int wave = tid >> 6;
    const int bbase = blockIdx.x * 64;

    if (wave == 0) {
        // ---------- right scan: u <- M[m] u for m = 63..1, store Ar[m-1] ----
        const int b = bbase + lane;
        const float4* xq = (const float4*)(x + (size_t)b * 128);
        float u0 = 1.f, u1 = 0.f, u2 = 0.f, u3 = 0.f;
        float4 xcur[4], xnxt[4];
        #pragma unroll
        for (int t = 0; t < 4; ++t) xcur[t] = xq[28 + t];       // sites 56..63
        #pragma unroll 1
        for (int c = 7; c >= 0; --c) {
            if (c > 0) {
                #pragma unroll
                for (int t = 0; t < 4; ++t) xnxt[t] = xq[(c - 1) * 4 + t];
            }
            #pragma unroll
            for (int k = 7; k >= 0; --k) {
                if (k == 0 && c == 0) continue;                 // skip m == 0
                const int m = c * 8 + k;
                // batch-load A[m] (32 floats) as 8 independent dwordx4
                float a[32];
                const float4* Aq = (const float4*)A + (size_t)m * 8;
                #pragma unroll
                for (int t = 0; t < 8; ++t) {
                    float4 q = Aq[t];
                    a[4*t] = q.x; a[4*t+1] = q.y; a[4*t+2] = q.z; a[4*t+3] = q.w;
                }
                float4 xp = xcur[k >> 1];
                const float xx = (k & 1) ? xp.z : xp.x;
                const float xy = (k & 1) ? xp.w : xp.y;
                const float inr = 1.f / sqrtf(xx * xx + xy * xy);
                const float xn0 = xx * inr, xn1 = xy * inr;
                const float uu[4] = {u0, u1, u2, u3};
                float vv[4];
                #pragma unroll
                for (int i = 0; i < 4; ++i) {                   // u' = M u
                    float acc = 0.f;
                    #pragma unroll
                    for (int j = 0; j < 4; ++j) {
                        float mm = fmaf(xn1, a[(i*4+j)*2+1], xn0 * a[(i*4+j)*2]);
                        acc = fmaf(mm, uu[j], acc);
                    }
                    vv[i] = acc;
                }
                u0 = vv[0]; u1 = vv[1]; u2 = vv[2]; u3 = vv[3];
                const float rn = 1.f / (sqrtf(u0*u0 + u1*u1 + u2*u2 + u3*u3) + EPS);
                const int o = ((m - 1) * 64 + lane) * 2;
                sAr[o]     = __floats2half2_rn(u0 * rn, u1 * rn);
                sAr[o + 1] = __floats2half2_rn(u2 * rn, u3 * rn);
            }
            if (c > 0) {
                #pragma unroll
                for (int t = 0; t < 4; ++t) xcur[t] = xnxt[t];
            }
        }
    } else if (wave == 1) {
        // ---------- left scan: w <- w^T M[m] for m = 0..62, store vL[m+1] ---
        const int b = bbase + lane;
        const float4* xq = (const float4*)(x + (size_t)b * 128);
        float w0 = 1.f, w1 = 0.f, w2 = 0.f, w3 = 0.f;
        float4 xcur[4], xnxt[4];
        #pragma unroll
        for (int t = 0; t < 4; ++t) xcur[t] = xq[t];            // sites 0..7
        #pragma unroll 1
        for (int c = 0; c < 8; ++c) {
            if (c < 7) {
                #pragma unroll
                for (int t = 0; t < 4; ++t) xnxt[t] = xq[(c + 1) * 4 + t];
            }
            #pragma unroll
            for (int k = 0; k < 8; ++k) {
                if (k == 7 && c == 7) continue;                 // skip m == 63
                const int m = c * 8 + k;
                float a[32];
                const float4* Aq = (const float4*)A + (size_t)m * 8;
                #pragma unroll
                for (int t = 0; t < 8; ++t) {
                    float4 q = Aq[t];
                    a[4*t] = q.x; a[4*t+1] = q.y; a[4*t+2] = q.z; a[4*t+3] = q.w;
                }
                float4 xp = xcur[k >> 1];
                const float xx = (k & 1) ? xp.z : xp.x;
                const float xy = (k & 1) ? xp.w : xp.y;
                const float inr = 1.f / sqrtf(xx * xx + xy * xy);
                const float xn0 = xx * inr, xn1 = xy * inr;
                const float ww[4] = {w0, w1, w2, w3};
                float tt[4] = {0.f, 0.f, 0.f, 0.f};
                #pragma unroll
                for (int i = 0; i < 4; ++i) {                   // w' = w^T M
                    #pragma unroll
                    for (int j = 0; j < 4; ++j) {
                        float mm = fmaf(xn1, a[(i*4+j)*2+1], xn0 * a[(i*4+j)*2]);
                        tt[j] = fmaf(ww[i], mm, tt[j]);
                    }
                }
                w0 = tt[0]; w1 = tt[1]; w2 = tt[2]; w3 = tt[3];
                const float rn = 1.f / (sqrtf(w0*w0 + w1*w1 + w2*w2 + w3*w3) + EPS);
                const int o = (m * 64 + lane) * 2;              // vL[m+1]
                sVl[o]     = __floats2half2_rn(w0 * rn, w1 * rn);
                sVl[o + 1] = __floats2half2_rn(w2 * rn, w3 * rn);
            }
            if (c < 7) {
                #pragma unroll
                for (int t = 0; t < 4; ++t) xcur[t] = xnxt[t];
            }
        }
    }

    __syncthreads();

    // ---------------- epilogue: 4 waves x 16 sites each ----------------------
    const float s = scale[0];
    const int eb = bbase + lane;
    const int nbase = wave * 16;
    const float* xb = x + (size_t)eb * 128;
    float*       yb = y + (size_t)eb * 128;

    #pragma unroll 2
    for (int k = 0; k < 16; ++k) {
        const int n = nbase + k;
        // batch-load B[n] (64 floats) as 16 independent dwordx4
        float4 bb[16];
        const float4* Bq = (const float4*)Bw + (size_t)n * 16;
        #pragma unroll
        for (int t = 0; t < 16; ++t) bb[t] = Bq[t];

        float vl[4], ar[4];
        if (n == 0) { vl[0] = 1.f; vl[1] = vl[2] = vl[3] = 0.f; }
        else {
            const int o = ((n - 1) * 64 + lane) * 2;
            float2 lo = __half22float2(sVl[o]);
            float2 hi = __half22float2(sVl[o + 1]);
            vl[0] = lo.x; vl[1] = lo.y; vl[2] = hi.x; vl[3] = hi.y;
        }
        if (n == 63) { ar[0] = 1.f; ar[1] = ar[2] = ar[3] = 0.f; }
        else {
            const int o = (n * 64 + lane) * 2;
            float2 lo = __half22float2(sAr[o]);
            float2 hi = __half22float2(sAr[o + 1]);
            ar[0] = lo.x; ar[1] = lo.y; ar[2] = hi.x; ar[3] = hi.y;
        }

        float2 xv = *(const float2*)(xb + n * 2);
        const float inr = 1.f / sqrtf(xv.x * xv.x + xv.y * xv.y);
        const float xn0 = xv.x * inr, xn1 = xv.y * inr;

        float H00 = 0.f, H01 = 0.f, H10 = 0.f, H11 = 0.f;
        #pragma unroll
        for (int i = 0; i < 4; ++i) {
            #pragma unroll
            for (int l = 0; l < 4; ++l) {
                const float cc = vl[i] * ar[l];
                const float4 q = bb[i * 4 + l];
                H00 = fmaf(cc, q.x, H00);
                H01 = fmaf(cc, q.y, H01);
                H10 = fmaf(cc, q.z, H10);
                H11 = fmaf(cc, q.w, H11);
            }
        }
        const float rh = s / (sqrtf(H00*H00 + H01*H01 + H10*H10 + H11*H11) + EPS);
        H00 *= rh; H01 *= rh; H10 *= rh; H11 *= rh;
        if (__builtin_isnan(H00)) H00 = 0.f;
        if (__builtin_isnan(H01)) H01 = 0.f;
        if (__builtin_isnan(H10)) H10 = 0.f;
        if (__builtin_isnan(H11)) H11 = 0.f;
        H00 = fmaxf(H00, 0.f); H01 = fmaxf(H01, 0.f);
        H10 = fmaxf(H10, 0.f); H11 = fmaxf(H11, 0.f);

        float2 yo;
        yo.x = fmaf(H01, xn1, H00 * xn0);
        yo.y = fmaf(H11, xn1, H10 * xn0);
        *(float2*)(yb + n * 2) = yo;
    }
}

extern "C" void kernel_launch(void* const* d_in, const int* in_sizes, int n_in,
                              void* d_out, int out_size, void* d_ws, size_t ws_size,
                              hipStream_t stream) {
    const float* x     = (const float*)d_in[0];
    const float* A     = (const float*)d_in[1];
    const float* B     = (const float*)d_in[2];
    const float* scale = (const float*)d_in[3];
    float* y = (float*)d_out;
    const int batch  = in_sizes[0] / (NSITES * 2);   // 16384
    const int blocks = batch / 64;                   // 256 blocks, 4 waves each
    tdvp_kernel<<<blocks, 256, 0, stream>>>(x, A, B, scale, y);
}